// Round 2
// baseline (2352.460 us; speedup 1.0000x reference)
//
#include <hip/hip_runtime.h>
#include <cstddef>

// Problem constants
#define NXS 64
#define NUS 32
#define NYS 32
#define NWS 64
#define BBATCH 256
#define TT  2048
#define UNR 4

// Workspace layout (floats):
//  [0,     4096)  Yinv (64x64)
//  [4096, 10240)  Wz  (96x64)
//  [10240,16384)  Wx  (96x64)  (Y_inv folded)
//  [16384,20480)  Wxw (64x64)  (Y_inv folded)
//  [20480,23552)  Wy  (96x32)
//  [23552,25600)  Wyw (64x32)

__device__ __forceinline__ float fast_tanh(float x) {
    float e = __expf(2.0f * x);
    return 1.0f - 2.0f * __builtin_amdgcn_rcpf(e + 1.0f);
}

// ---------------------------------------------------------------------------
__global__ __launch_bounds__(256) void invert_kernel(const float* __restrict__ Y,
                                                     float* __restrict__ ws) {
    __shared__ float M[64 * 129];
    __shared__ float rowk[128];
    __shared__ float ck[64];
    const int tid = threadIdx.x;

    for (int idx = tid; idx < 64 * 64; idx += 256) {
        int r = idx >> 6, c = idx & 63;
        M[r * 129 + c]      = Y[idx];
        M[r * 129 + 64 + c] = (r == c) ? 1.0f : 0.0f;
    }
    __syncthreads();

    for (int k = 0; k < 64; ++k) {
        float dv = 1.0f / M[k * 129 + k];
        if (tid < 128) rowk[tid] = M[k * 129 + tid] * dv;
        if (tid >= 128 && tid < 192) ck[tid - 128] = M[(tid - 128) * 129 + k];
        __syncthreads();
        for (int idx = tid; idx < 64 * 128; idx += 256) {
            int r = idx >> 7, c = idx & 127;
            float cur = M[r * 129 + c];
            M[r * 129 + c] = (r == k) ? rowk[c] : cur - ck[r] * rowk[c];
        }
        __syncthreads();
    }

    for (int idx = tid; idx < 64 * 64; idx += 256) {
        int r = idx >> 6, c = idx & 63;
        ws[idx] = M[r * 129 + 64 + c];
    }
}

// ---------------------------------------------------------------------------
__global__ __launch_bounds__(256) void prep_kernel(const float* __restrict__ lam,
                                                   const float* __restrict__ A,
                                                   const float* __restrict__ B1,
                                                   const float* __restrict__ B2,
                                                   const float* __restrict__ C1,
                                                   const float* __restrict__ D11,
                                                   const float* __restrict__ D12,
                                                   const float* __restrict__ C2,
                                                   const float* __restrict__ D21,
                                                   float* __restrict__ ws) {
    const float* __restrict__ Yinv = ws;
    int e = blockIdx.x * 256 + threadIdx.x;
    if (e >= 21504) return;

    if (e < 6144) {
        int k = e >> 6, j = e & 63;
        float ti = 1.0f / lam[j];
        float v = (k < 64) ? C2[j * 64 + k] : D21[j * 32 + (k - 64)];
        ws[4096 + e] = v * ti;
    } else if (e < 12288) {
        int e2 = e - 6144;
        int k = e2 >> 6, j = e2 & 63;
        float s = 0.0f;
        if (k < 64) {
            #pragma unroll 8
            for (int m = 0; m < 64; ++m) s += A[m * 64 + k] * Yinv[m * 64 + j];
        } else {
            int ku = k - 64;
            #pragma unroll 8
            for (int m = 0; m < 64; ++m) s += B1[m * 32 + ku] * Yinv[m * 64 + j];
        }
        ws[10240 + e2] = s;
    } else if (e < 16384) {
        int e2 = e - 12288;
        int k = e2 >> 6, j = e2 & 63;
        float s = 0.0f;
        #pragma unroll 8
        for (int m = 0; m < 64; ++m) s += B2[m * 64 + k] * Yinv[m * 64 + j];
        ws[16384 + e2] = s;
    } else if (e < 19456) {
        int e2 = e - 16384;
        int k = e2 >> 5, j = e2 & 31;
        ws[20480 + e2] = (k < 64) ? C1[j * 64 + k] : D11[j * 32 + (k - 64)];
    } else {
        int e2 = e - 19456;
        int k = e2 >> 5, j = e2 & 31;
        ws[23552 + e2] = D12[j * 64 + k];
    }
}

// ---------------------------------------------------------------------------
// Scan kernel: 128 blocks x 512 threads. Chain c = tid>>8 (2 chains/block ->
// 2 waves/SIMD for HW latency hiding). Per chain: waves 0,1 = ZY (z->tanh->w,
// then y), waves 2,3 = XN (x_next).  Activation buffer sbuf = [x(64);u(32);
// w(64)] so every K-slice is contiguous float4s.  Output partition: lane
// (o = l>>3, p = l&7) computes R outputs j = o+16m over K-slice p (P=8),
// butterfly-reduced over the 3 low lane bits.  u staged in LDS 16 steps at a
// time (global load at t%16==0, LDS write at t%16==8 -> no vmcnt stall);
// y batched UNR steps in registers.
__global__ __launch_bounds__(512, 2) void rnn_kernel(const float* __restrict__ xp,
                                                     const float* __restrict__ ws,
                                                     float* __restrict__ out) {
    const int tid = threadIdx.x;
    const int c   = tid >> 8;          // chain slot in block
    const int lt  = tid & 255;         // within-chain thread
    const int bc  = blockIdx.x * 2 + c;

    __shared__ __align__(16) float sbuf[2][2][160];    // pingpong x chain x [x;u;w]
    __shared__ __align__(16) float ustage[2][16][2][32];

    const float* __restrict__ Wz  = ws + 4096;
    const float* __restrict__ Wx  = ws + 10240;
    const float* __restrict__ Wxw = ws + 16384;
    const float* __restrict__ Wy  = ws + 20480;
    const float* __restrict__ Wyw = ws + 23552;

    const float4* __restrict__ xp4 = (const float4*)(xp + (size_t)bc * (TT * NUS));
    const size_t yb = (size_t)bc * (TT * NYS);

    // ---- prologue: x0 = 0, u[0] into sbuf, u[0..15] into ustage[0] ----
    if (lt < 16) ((float4*)&sbuf[0][c][0])[lt] = make_float4(0.f, 0.f, 0.f, 0.f);
    if (lt >= 16 && lt < 24) ((float4*)&sbuf[0][c][64])[lt - 16] = xp4[lt - 16];
    if (lt >= 128) {
        int xl = lt - 128, st = xl >> 3, k4 = xl & 7;
        ((float4*)&ustage[0][st][c][0])[k4] = xp4[st * 8 + k4];
    }
    __syncthreads();

    if (lt < 128) {
        // ======================= ZY waves =======================
        const int o = lt >> 3, p = lt & 7;
        float wz[12][4], wy[20][2];
        #pragma unroll
        for (int i = 0; i < 12; ++i) {
            const float* r = Wz + (12 * p + i) * 64 + o;
            wz[i][0] = r[0]; wz[i][1] = r[16]; wz[i][2] = r[32]; wz[i][3] = r[48];
        }
        #pragma unroll
        for (int i = 0; i < 20; ++i) {
            int kk = 20 * p + i;
            const float* r = (kk < 96) ? (Wy + kk * 32 + o) : (Wyw + (kk - 96) * 32 + o);
            wy[i][0] = r[0]; wy[i][1] = r[16];
        }

        float ybatch[UNR];
        for (int tb = 0; tb < TT; tb += UNR) {
            #pragma unroll
            for (int s = 0; s < UNR; ++s) {
                const int pp = s & 1;              // tb even
                const float4* sb4 = (const float4*)&sbuf[pp][c][0];

                // ---- z: K-slice p (12 floats), 4 outputs ----
                float act[12];
                *(float4*)&act[0] = sb4[3 * p];
                *(float4*)&act[4] = sb4[3 * p + 1];
                *(float4*)&act[8] = sb4[3 * p + 2];
                float az0 = 0.f, az1 = 0.f, az2 = 0.f, az3 = 0.f;
                #pragma unroll
                for (int i = 0; i < 12; ++i) {
                    az0 += act[i] * wz[i][0]; az1 += act[i] * wz[i][1];
                    az2 += act[i] * wz[i][2]; az3 += act[i] * wz[i][3];
                }
                az0 += __shfl_xor(az0, 1); az1 += __shfl_xor(az1, 1);
                az2 += __shfl_xor(az2, 1); az3 += __shfl_xor(az3, 1);
                az0 += __shfl_xor(az0, 2); az1 += __shfl_xor(az1, 2);
                az2 += __shfl_xor(az2, 2); az3 += __shfl_xor(az3, 2);
                az0 += __shfl_xor(az0, 4); az1 += __shfl_xor(az1, 4);
                az2 += __shfl_xor(az2, 4); az3 += __shfl_xor(az3, 4);
                if (p < 4) {
                    float zz = (p == 0) ? az0 : (p == 1) ? az1 : (p == 2) ? az2 : az3;
                    sbuf[pp][c][96 + o + 16 * p] = fast_tanh(zz);
                }
                __syncthreads();                   // barrier 1: w published

                // ---- y: K-slice p (20 floats of [x;u;w]), 2 outputs ----
                float acty[20];
                *(float4*)&acty[0]  = sb4[5 * p];
                *(float4*)&acty[4]  = sb4[5 * p + 1];
                *(float4*)&acty[8]  = sb4[5 * p + 2];
                *(float4*)&acty[12] = sb4[5 * p + 3];
                *(float4*)&acty[16] = sb4[5 * p + 4];
                float ya0 = 0.f, ya1 = 0.f;
                #pragma unroll
                for (int i = 0; i < 20; ++i) {
                    ya0 += acty[i] * wy[i][0]; ya1 += acty[i] * wy[i][1];
                }
                ya0 += __shfl_xor(ya0, 1); ya1 += __shfl_xor(ya1, 1);
                ya0 += __shfl_xor(ya0, 2); ya1 += __shfl_xor(ya1, 2);
                ya0 += __shfl_xor(ya0, 4); ya1 += __shfl_xor(ya1, 4);
                ybatch[s] = (p == 0) ? ya0 : ya1;
                __syncthreads();                   // barrier 2: step done
            }
            if (p < 2) {                           // batched y flush
                size_t base = yb + (size_t)tb * NYS + (o + 16 * p);
                #pragma unroll
                for (int s = 0; s < UNR; ++s) out[base + s * NYS] = ybatch[s];
            }
        }
    } else {
        // ======================= XN waves =======================
        const int xl = lt - 128;
        const int o = xl >> 3, p = xl & 7;
        float wxr[12][4], wxwr[8][4];
        #pragma unroll
        for (int i = 0; i < 12; ++i) {
            const float* r = Wx + (12 * p + i) * 64 + o;
            wxr[i][0] = r[0]; wxr[i][1] = r[16]; wxr[i][2] = r[32]; wxr[i][3] = r[48];
        }
        #pragma unroll
        for (int i = 0; i < 8; ++i) {
            const float* r = Wxw + (8 * p + i) * 64 + o;
            wxwr[i][0] = r[0]; wxwr[i][1] = r[16]; wxwr[i][2] = r[32]; wxwr[i][3] = r[48];
        }

        float4 ureg = make_float4(0.f, 0.f, 0.f, 0.f);
        for (int tb = 0; tb < TT; tb += UNR) {
            #pragma unroll
            for (int s = 0; s < UNR; ++s) {
                const int t  = tb + s;
                const int pp = s & 1;
                const float4* sb4 = (const float4*)&sbuf[pp][c][0];

                // chunk-top: issue next u-chunk loads (st = o, fl4 = p)
                if ((t & 15) == 0 && t + 16 < TT)
                    ureg = xp4[(t + 16 + o) * 8 + p];

                // ---- x' (x,u part): K-slice p (12 floats), 4 outputs ----
                float act[12];
                *(float4*)&act[0] = sb4[3 * p];
                *(float4*)&act[4] = sb4[3 * p + 1];
                *(float4*)&act[8] = sb4[3 * p + 2];
                float ax0 = 0.f, ax1 = 0.f, ax2 = 0.f, ax3 = 0.f;
                #pragma unroll
                for (int i = 0; i < 12; ++i) {
                    ax0 += act[i] * wxr[i][0]; ax1 += act[i] * wxr[i][1];
                    ax2 += act[i] * wxr[i][2]; ax3 += act[i] * wxr[i][3];
                }
                __syncthreads();                   // barrier 1: w available

                // park u-chunk into LDS (load long since retired -> no stall)
                if ((t & 15) == 8 && t + 8 < TT) {
                    int nb = ((t >> 4) & 1) ^ 1;
                    ((float4*)&ustage[nb][o][c][0])[p] = ureg;
                }

                // ---- x' (w part): K-slice p (8 floats) ----
                float actw[8];
                *(float4*)&actw[0] = sb4[24 + 2 * p];
                *(float4*)&actw[4] = sb4[24 + 2 * p + 1];
                #pragma unroll
                for (int i = 0; i < 8; ++i) {
                    ax0 += actw[i] * wxwr[i][0]; ax1 += actw[i] * wxwr[i][1];
                    ax2 += actw[i] * wxwr[i][2]; ax3 += actw[i] * wxwr[i][3];
                }
                ax0 += __shfl_xor(ax0, 1); ax1 += __shfl_xor(ax1, 1);
                ax2 += __shfl_xor(ax2, 1); ax3 += __shfl_xor(ax3, 1);
                ax0 += __shfl_xor(ax0, 2); ax1 += __shfl_xor(ax1, 2);
                ax2 += __shfl_xor(ax2, 2); ax3 += __shfl_xor(ax3, 2);
                ax0 += __shfl_xor(ax0, 4); ax1 += __shfl_xor(ax1, 4);
                ax2 += __shfl_xor(ax2, 4); ax3 += __shfl_xor(ax3, 4);
                if (p < 4) {
                    float xv = (p == 0) ? ax0 : (p == 1) ? ax1 : (p == 2) ? ax2 : ax3;
                    sbuf[pp ^ 1][c][o + 16 * p] = xv;
                }
                // copy u[t+1] from ustage into next sbuf
                if (xl < 8 && t + 1 < TT) {
                    int cbn = ((t + 1) >> 4) & 1, stn = (t + 1) & 15;
                    ((float4*)&sbuf[pp ^ 1][c][64])[xl] =
                        ((const float4*)&ustage[cbn][stn][c][0])[xl];
                }
                __syncthreads();                   // barrier 2: x' published
            }
        }
    }

    __syncthreads();
    // x_final = x(2048), written into sbuf[0] at t=2047
    if (lt < 64)
        out[(size_t)BBATCH * TT * NYS + (size_t)bc * 64 + lt] = sbuf[0][c][lt];
}

// ---------------------------------------------------------------------------
extern "C" void kernel_launch(void* const* d_in, const int* in_sizes, int n_in,
                              void* d_out, int out_size, void* d_ws, size_t ws_size,
                              hipStream_t stream) {
    const float* xp  = (const float*)d_in[0];
    const float* Y   = (const float*)d_in[1];
    const float* lam = (const float*)d_in[2];
    const float* A   = (const float*)d_in[3];
    const float* B1  = (const float*)d_in[4];
    const float* B2  = (const float*)d_in[5];
    const float* C1  = (const float*)d_in[6];
    const float* D11 = (const float*)d_in[7];
    const float* D12 = (const float*)d_in[8];
    const float* C2  = (const float*)d_in[9];
    const float* D21 = (const float*)d_in[10];
    float* out = (float*)d_out;
    float* ws  = (float*)d_ws;

    hipLaunchKernelGGL(invert_kernel, dim3(1),   dim3(256), 0, stream, Y, ws);
    hipLaunchKernelGGL(prep_kernel,   dim3(84),  dim3(256), 0, stream,
                       lam, A, B1, B2, C1, D11, D12, C2, D21, ws);
    hipLaunchKernelGGL(rnn_kernel,    dim3(128), dim3(512), 0, stream, xp, ws, out);
}

// Round 3
// 1852.733 us; speedup vs baseline: 1.2697x; 1.2697x over previous
//
#include <hip/hip_runtime.h>
#include <cstddef>

#define NXS 64
#define NUS 32
#define NYS 32
#define NWS 64
#define BBATCH 256
#define TT  2048

// ws float layout:
//  [0,     12288)  Wzt (192x64): rows 0..95  = Wzz = Wx@(C2^T Tinv)   ([x;u] -> z')
//                                rows 96..159= Wwz = Wxw@(C2^T Tinv)  (w -> z')
//                                rows 160..191= Wzu = D21^T Tinv      (u' -> z')
//  [12288, 18432)  Wx  (96x64)  [x;u] -> x'   (Yinv folded)
//  [18432, 22528)  Wxw (64x64)  w -> x'       (Yinv folded)
//  [22528, 27648)  Wyt (160x32) [x;u;w] -> y

#define WS_WZT  0
#define WS_WX   12288
#define WS_WXW  18432
#define WS_WYT  22528

__device__ __forceinline__ float fast_tanh(float x) {
    float e = __expf(2.0f * x);
    return 1.0f - 2.0f * __builtin_amdgcn_rcpf(e + 1.0f);
}

// ---------------------------------------------------------------------------
// Fused setup: Gauss-Jordan inverse of Y (in LDS), then all fused weights.
__global__ __launch_bounds__(256) void setup_kernel(const float* __restrict__ Y,
                                                    const float* __restrict__ lam,
                                                    const float* __restrict__ A,
                                                    const float* __restrict__ B1,
                                                    const float* __restrict__ B2,
                                                    const float* __restrict__ C1,
                                                    const float* __restrict__ D11,
                                                    const float* __restrict__ D12,
                                                    const float* __restrict__ C2,
                                                    const float* __restrict__ D21,
                                                    float* __restrict__ ws) {
    __shared__ float M[64 * 129];      // [Y | I] -> [I | Yinv], pad 129
    __shared__ float rowk[128];
    __shared__ float ck[64];
    __shared__ float WxL[96 * 64];
    __shared__ float WxwL[64 * 64];
    const int tid = threadIdx.x;

    for (int idx = tid; idx < 64 * 64; idx += 256) {
        int r = idx >> 6, c = idx & 63;
        M[r * 129 + c]      = Y[idx];
        M[r * 129 + 64 + c] = (r == c) ? 1.0f : 0.0f;
    }
    __syncthreads();

    for (int k = 0; k < 64; ++k) {
        float dv = 1.0f / M[k * 129 + k];
        if (tid < 128) rowk[tid] = M[k * 129 + tid] * dv;
        if (tid >= 128 && tid < 192) ck[tid - 128] = M[(tid - 128) * 129 + k];
        __syncthreads();
        for (int idx = tid; idx < 64 * 128; idx += 256) {
            int r = idx >> 7, c = idx & 127;
            float cur = M[r * 129 + c];
            M[r * 129 + c] = (r == k) ? rowk[c] : cur - ck[r] * rowk[c];
        }
        __syncthreads();
    }
    // Yinv[m][j] = M[m*129 + 64 + j]

    // phase 2: Wx, Wxw (cache in LDS too), Wzu, Wyt
    for (int idx = tid; idx < 6144; idx += 256) {        // Wx
        int k = idx >> 6, j = idx & 63;
        float s = 0.0f;
        if (k < 64) {
            #pragma unroll 8
            for (int m = 0; m < 64; ++m) s += A[m * 64 + k] * M[m * 129 + 64 + j];
        } else {
            int ku = k - 64;
            #pragma unroll 8
            for (int m = 0; m < 64; ++m) s += B1[m * 32 + ku] * M[m * 129 + 64 + j];
        }
        WxL[idx] = s;
        ws[WS_WX + idx] = s;
    }
    for (int idx = tid; idx < 4096; idx += 256) {        // Wxw
        int k = idx >> 6, j = idx & 63;
        float s = 0.0f;
        #pragma unroll 8
        for (int m = 0; m < 64; ++m) s += B2[m * 64 + k] * M[m * 129 + 64 + j];
        WxwL[idx] = s;
        ws[WS_WXW + idx] = s;
    }
    for (int idx = tid; idx < 2048; idx += 256) {        // Wzu rows 160..191
        int k = idx >> 6, j = idx & 63;
        ws[WS_WZT + 10240 + idx] = D21[j * 32 + k] / lam[j];
    }
    for (int idx = tid; idx < 5120; idx += 256) {        // Wyt
        int k = idx >> 5, j = idx & 31;
        float v = (k < 64) ? C1[j * 64 + k]
                : (k < 96) ? D11[j * 32 + (k - 64)]
                           : D12[j * 64 + (k - 96)];
        ws[WS_WYT + idx] = v;
    }
    __syncthreads();

    // phase 3: Wzz, Wwz
    for (int idx = tid; idx < 6144; idx += 256) {        // Wzz rows 0..95
        int k = idx >> 6, j = idx & 63;
        float s = 0.0f;
        #pragma unroll 8
        for (int m = 0; m < 64; ++m) s += WxL[k * 64 + m] * C2[j * 64 + m];
        ws[WS_WZT + idx] = s / lam[j];
    }
    for (int idx = tid; idx < 4096; idx += 256) {        // Wwz rows 96..159
        int k = idx >> 6, j = idx & 63;
        float s = 0.0f;
        #pragma unroll 8
        for (int m = 0; m < 64; ++m) s += WxwL[k * 64 + m] * C2[j * 64 + m];
        ws[WS_WZT + 6144 + idx] = s / lam[j];
    }
}

// ---------------------------------------------------------------------------
// Scan: 256 blocks (1 chain) x 512 threads (8 waves, 2/SIMD).
// One barrier per step. S vector (192 floats) = [x(64); u(32); w(64); uq(32)],
// ping-pong in LDS.  Iteration i: reads S_{i-1}, writes S_i:
//   waves 0-3 (Z): z_i = S_{i-1} @ Wzt; w_i = tanh(z_i)     (K=192)
//   waves 4-7 (X): x_i = S_{i-1}[0:160] @ [Wx;Wxw]          (K=160)
//                  y_{i-1} = S_{i-1}[0:160] @ Wyt  (same act slice, batched store)
// Lane mapping per wave: p = lane&15 (K-slice, butterfly-reduced via
// shfl_xor 1/2/4/8), o = lane>>4; R=4 outputs j = 16g + o + 4r.
__global__ __launch_bounds__(512, 2) void rnn_kernel(const float* __restrict__ xp,
                                                     const float* __restrict__ ws,
                                                     float* __restrict__ out) {
    const int b    = blockIdx.x;
    const int tid  = threadIdx.x;
    const int wave = tid >> 6;
    const int lane = tid & 63;
    const int p    = lane & 15;
    const int o    = lane >> 4;

    __shared__ __align__(16) float sbuf[2][192];
    __shared__ __align__(16) float ustage[2 * 512];     // 2 rings x 16 steps x 32

    const float* __restrict__ Wzt = ws + WS_WZT;
    const float* __restrict__ Wx  = ws + WS_WX;
    const float* __restrict__ Wxw = ws + WS_WXW;
    const float* __restrict__ Wyt = ws + WS_WYT;

    const float4* __restrict__ xp4 = (const float4*)(xp + (size_t)b * (TT * NUS));
    float4* ust4 = (float4*)ustage;
    const size_t yb   = (size_t)b * (TT * NYS);
    const size_t xoff = (size_t)BBATCH * TT * NYS;

    // prologue: S_{-1} = [0;0;0;u_0] in sbuf[1]; ustage ring0 = u_0..15
    if (tid < 40)               ((float4*)&sbuf[1][0])[tid] = make_float4(0.f, 0.f, 0.f, 0.f);
    if (tid >= 40 && tid < 48)  ((float4*)&sbuf[1][160])[tid - 40] = xp4[tid - 40];
    if (tid >= 128 && tid < 256) ust4[tid - 128] = xp4[tid - 128];
    __syncthreads();

    if (wave < 4) {
        // ===================== Z waves: z -> tanh -> w =====================
        const int g  = wave;
        const int jz = 16 * g + o;
        float wz[12][4];
        #pragma unroll
        for (int i = 0; i < 12; ++i) {
            const float* rr = Wzt + (12 * p + i) * 64 + jz;
            wz[i][0] = rr[0]; wz[i][1] = rr[4]; wz[i][2] = rr[8]; wz[i][3] = rr[12];
        }

        float4 ur0 = make_float4(0.f, 0.f, 0.f, 0.f);
        float4 ur1 = ur0;

        #pragma unroll 4
        for (int i = 0; i < TT; ++i) {
            const int rp = (i + 1) & 1, wp = i & 1;
            const float4* sb4 = (const float4*)&sbuf[rp][0];

            // wave 2: global u prefetch machinery (off critical path)
            if (g == 2) {
                if ((i & 15) == 0 && i + 16 < TT) {
                    int base = (i + 16) * 8;
                    ur0 = xp4[base + lane];
                    ur1 = xp4[base + 64 + lane];
                }
                if ((i & 15) == 8) {
                    int nb = ((i >> 4) + 1) & 1;
                    ust4[nb * 128 + lane]      = ur0;
                    ust4[nb * 128 + 64 + lane] = ur1;
                }
            }

            // act slice: 12 floats at [12p, 12p+12)
            float act[12];
            *(float4*)&act[0] = sb4[3 * p];
            *(float4*)&act[4] = sb4[3 * p + 1];
            *(float4*)&act[8] = sb4[3 * p + 2];

            float az0 = 0.f, az1 = 0.f, az2 = 0.f, az3 = 0.f;
            #pragma unroll
            for (int k = 0; k < 12; ++k) {
                az0 += act[k] * wz[k][0]; az1 += act[k] * wz[k][1];
                az2 += act[k] * wz[k][2]; az3 += act[k] * wz[k][3];
            }
            az0 += __shfl_xor(az0, 1); az1 += __shfl_xor(az1, 1);
            az2 += __shfl_xor(az2, 1); az3 += __shfl_xor(az3, 1);
            az0 += __shfl_xor(az0, 2); az1 += __shfl_xor(az1, 2);
            az2 += __shfl_xor(az2, 2); az3 += __shfl_xor(az3, 2);
            az0 += __shfl_xor(az0, 4); az1 += __shfl_xor(az1, 4);
            az2 += __shfl_xor(az2, 4); az3 += __shfl_xor(az3, 4);
            az0 += __shfl_xor(az0, 8); az1 += __shfl_xor(az1, 8);
            az2 += __shfl_xor(az2, 8); az3 += __shfl_xor(az3, 8);
            float w0 = fast_tanh(az0), w1 = fast_tanh(az1);
            float w2 = fast_tanh(az2), w3 = fast_tanh(az3);
            if (p == 0) {
                sbuf[wp][96 + jz]      = w0;
                sbuf[wp][96 + jz + 4]  = w1;
                sbuf[wp][96 + jz + 8]  = w2;
                sbuf[wp][96 + jz + 12] = w3;
            }

            // u plumbing: S_i.u <- S_{i-1}.uq ; S_i.uq <- u_{i+1} (from ustage)
            if (g == 0 && lane < 8)
                ((float4*)&sbuf[wp][64])[lane] = ((const float4*)&sbuf[rp][160])[lane];
            if (g == 1 && lane < 8) {
                int s = i + 1;
                int cb = (s >> 4) & 1;
                ((float4*)&sbuf[wp][160])[lane] = ust4[cb * 128 + (s & 15) * 8 + lane];
            }
            __syncthreads();
        }
    } else {
        // ===================== X waves: x' and y =====================
        const int g  = wave - 4;
        const int jx = 16 * g + o;
        const int jy = 8 * g + o;
        float wx[10][4], wy[10][2];
        #pragma unroll
        for (int i = 0; i < 10; ++i) {
            int row = 10 * p + i;
            const float* rr = (row < 96) ? (Wx + row * 64 + jx)
                                         : (Wxw + (row - 96) * 64 + jx);
            wx[i][0] = rr[0]; wx[i][1] = rr[4]; wx[i][2] = rr[8]; wx[i][3] = rr[12];
            const float* ry = Wyt + row * 32 + jy;
            wy[i][0] = ry[0]; wy[i][1] = ry[4];
        }

        float yb0[4], yb1[4];
        #pragma unroll
        for (int s = 0; s < 4; ++s) { yb0[s] = 0.f; yb1[s] = 0.f; }

        #pragma unroll 4
        for (int i = 0; i < TT; ++i) {
            const int rp = (i + 1) & 1, wp = i & 1;
            const float2* sb2 = (const float2*)&sbuf[rp][0];

            // act slice: 10 floats at [10p, 10p+10)
            float act[10];
            *(float2*)&act[0] = sb2[5 * p];
            *(float2*)&act[2] = sb2[5 * p + 1];
            *(float2*)&act[4] = sb2[5 * p + 2];
            *(float2*)&act[6] = sb2[5 * p + 3];
            *(float2*)&act[8] = sb2[5 * p + 4];

            float ax0 = 0.f, ax1 = 0.f, ax2 = 0.f, ax3 = 0.f;
            float ay0 = 0.f, ay1 = 0.f;
            #pragma unroll
            for (int k = 0; k < 10; ++k) {
                ax0 += act[k] * wx[k][0]; ax1 += act[k] * wx[k][1];
                ax2 += act[k] * wx[k][2]; ax3 += act[k] * wx[k][3];
                ay0 += act[k] * wy[k][0]; ay1 += act[k] * wy[k][1];
            }
            ax0 += __shfl_xor(ax0, 1); ax1 += __shfl_xor(ax1, 1);
            ax2 += __shfl_xor(ax2, 1); ax3 += __shfl_xor(ax3, 1);
            ay0 += __shfl_xor(ay0, 1); ay1 += __shfl_xor(ay1, 1);
            ax0 += __shfl_xor(ax0, 2); ax1 += __shfl_xor(ax1, 2);
            ax2 += __shfl_xor(ax2, 2); ax3 += __shfl_xor(ax3, 2);
            ay0 += __shfl_xor(ay0, 2); ay1 += __shfl_xor(ay1, 2);
            ax0 += __shfl_xor(ax0, 4); ax1 += __shfl_xor(ax1, 4);
            ax2 += __shfl_xor(ax2, 4); ax3 += __shfl_xor(ax3, 4);
            ay0 += __shfl_xor(ay0, 4); ay1 += __shfl_xor(ay1, 4);
            ax0 += __shfl_xor(ax0, 8); ax1 += __shfl_xor(ax1, 8);
            ax2 += __shfl_xor(ax2, 8); ax3 += __shfl_xor(ax3, 8);
            ay0 += __shfl_xor(ay0, 8); ay1 += __shfl_xor(ay1, 8);

            if (p == 0) {
                sbuf[wp][jx]      = ax0;
                sbuf[wp][jx + 4]  = ax1;
                sbuf[wp][jx + 8]  = ax2;
                sbuf[wp][jx + 12] = ax3;
            }
            // y_{i-1} into batch slot (i-1)&3 (i=0 writes harmless zeros-based y)
            yb0[(i + 3) & 3] = ay0;
            yb1[(i + 3) & 3] = ay1;
            if ((i & 3) == 0 && i >= 4 && p == 0) {
                size_t base = yb + (size_t)(i - 4) * NYS + jy;
                #pragma unroll
                for (int s = 0; s < 4; ++s) {
                    out[base + s * NYS]     = yb0[s];
                    out[base + s * NYS + 4] = yb1[s];
                }
            }
            __syncthreads();
        }

        // ---- epilogue: y_2047 and x_final = x_2048, from S_2047 (sbuf[1]) ----
        {
            const float2* sb2 = (const float2*)&sbuf[1][0];
            float act[10];
            *(float2*)&act[0] = sb2[5 * p];
            *(float2*)&act[2] = sb2[5 * p + 1];
            *(float2*)&act[4] = sb2[5 * p + 2];
            *(float2*)&act[6] = sb2[5 * p + 3];
            *(float2*)&act[8] = sb2[5 * p + 4];
            float ax0 = 0.f, ax1 = 0.f, ax2 = 0.f, ax3 = 0.f;
            float ay0 = 0.f, ay1 = 0.f;
            #pragma unroll
            for (int k = 0; k < 10; ++k) {
                ax0 += act[k] * wx[k][0]; ax1 += act[k] * wx[k][1];
                ax2 += act[k] * wx[k][2]; ax3 += act[k] * wx[k][3];
                ay0 += act[k] * wy[k][0]; ay1 += act[k] * wy[k][1];
            }
            ax0 += __shfl_xor(ax0, 1); ax1 += __shfl_xor(ax1, 1);
            ax2 += __shfl_xor(ax2, 1); ax3 += __shfl_xor(ax3, 1);
            ay0 += __shfl_xor(ay0, 1); ay1 += __shfl_xor(ay1, 1);
            ax0 += __shfl_xor(ax0, 2); ax1 += __shfl_xor(ax1, 2);
            ax2 += __shfl_xor(ax2, 2); ax3 += __shfl_xor(ax3, 2);
            ay0 += __shfl_xor(ay0, 2); ay1 += __shfl_xor(ay1, 2);
            ax0 += __shfl_xor(ax0, 4); ax1 += __shfl_xor(ax1, 4);
            ax2 += __shfl_xor(ax2, 4); ax3 += __shfl_xor(ax3, 4);
            ay0 += __shfl_xor(ay0, 4); ay1 += __shfl_xor(ay1, 4);
            ax0 += __shfl_xor(ax0, 8); ax1 += __shfl_xor(ax1, 8);
            ax2 += __shfl_xor(ax2, 8); ax3 += __shfl_xor(ax3, 8);
            ay0 += __shfl_xor(ay0, 8); ay1 += __shfl_xor(ay1, 8);
            yb0[3] = ay0; yb1[3] = ay1;     // y_2047
            if (p == 0) {
                out[xoff + (size_t)b * 64 + jx]      = ax0;
                out[xoff + (size_t)b * 64 + jx + 4]  = ax1;
                out[xoff + (size_t)b * 64 + jx + 8]  = ax2;
                out[xoff + (size_t)b * 64 + jx + 12] = ax3;
                size_t base = yb + (size_t)2044 * NYS + jy;
                #pragma unroll
                for (int s = 0; s < 4; ++s) {
                    out[base + s * NYS]     = yb0[s];
                    out[base + s * NYS + 4] = yb1[s];
                }
            }
        }
    }
}

// ---------------------------------------------------------------------------
extern "C" void kernel_launch(void* const* d_in, const int* in_sizes, int n_in,
                              void* d_out, int out_size, void* d_ws, size_t ws_size,
                              hipStream_t stream) {
    const float* xp  = (const float*)d_in[0];
    const float* Y   = (const float*)d_in[1];
    const float* lam = (const float*)d_in[2];
    const float* A   = (const float*)d_in[3];
    const float* B1  = (const float*)d_in[4];
    const float* B2  = (const float*)d_in[5];
    const float* C1  = (const float*)d_in[6];
    const float* D11 = (const float*)d_in[7];
    const float* D12 = (const float*)d_in[8];
    const float* C2  = (const float*)d_in[9];
    const float* D21 = (const float*)d_in[10];
    float* out = (float*)d_out;
    float* ws  = (float*)d_ws;

    hipLaunchKernelGGL(setup_kernel, dim3(1), dim3(256), 0, stream,
                       Y, lam, A, B1, B2, C1, D11, D12, C2, D21, ws);
    hipLaunchKernelGGL(rnn_kernel, dim3(256), dim3(512), 0, stream, xp, ws, out);
}

// Round 4
// 1317.384 us; speedup vs baseline: 1.7857x; 1.4064x over previous
//
#include <hip/hip_runtime.h>
#include <cstddef>

#define NXS 64
#define NUS 32
#define NYS 32
#define NWS 64
#define BBATCH 256
#define TT  2048

// ws float layout:
//  [0,     12288)  Wzt (192x64): rows 0..95 Wzz=[A;B1]tilde@C2tTinv, 96..159 Wwz, 160..191 Wzu=D21tTinv
//  [12288, 24576)  Wxt (192x64): rows 0..95 Wx (Yinv folded), 96..159 Wxw, 160..191 ZERO
//  [24576, 30720)  Wyt (192x32): rows 0..159 [C1;D11;D12], 160..191 ZERO
#define WS_WZT  0
#define WS_WXT  12288
#define WS_WYT  24576

typedef float v2f __attribute__((ext_vector_type(2)));

__device__ __forceinline__ float fast_tanh(float x) {
    float e = __expf(2.0f * x);
    return 1.0f - 2.0f * __builtin_amdgcn_rcpf(e + 1.0f);
}

// Row-of-16 all-lanes sum via DPP row rotates (VALU-only, no LDS pipe).
template<int CTRL>
__device__ __forceinline__ float dpp_row_add(float v) {
    int t = __builtin_amdgcn_update_dpp(0, __float_as_int(v), CTRL, 0xF, 0xF, true);
    return v + __int_as_float(t);
}
__device__ __forceinline__ float row_sum16(float v) {
    v = dpp_row_add<0x121>(v);   // row_ror:1
    v = dpp_row_add<0x122>(v);   // row_ror:2
    v = dpp_row_add<0x124>(v);   // row_ror:4
    v = dpp_row_add<0x128>(v);   // row_ror:8
    return v;
}

// ---------------------------------------------------------------------------
__global__ __launch_bounds__(256) void setup_kernel(const float* __restrict__ Y,
                                                    const float* __restrict__ lam,
                                                    const float* __restrict__ A,
                                                    const float* __restrict__ B1,
                                                    const float* __restrict__ B2,
                                                    const float* __restrict__ C1,
                                                    const float* __restrict__ D11,
                                                    const float* __restrict__ D12,
                                                    const float* __restrict__ C2,
                                                    const float* __restrict__ D21,
                                                    float* __restrict__ ws) {
    __shared__ float M[64 * 129];
    __shared__ float rowk[128];
    __shared__ float ck[64];
    __shared__ float WxL[96 * 64];
    __shared__ float WxwL[64 * 64];
    const int tid = threadIdx.x;

    for (int idx = tid; idx < 64 * 64; idx += 256) {
        int r = idx >> 6, c = idx & 63;
        M[r * 129 + c]      = Y[idx];
        M[r * 129 + 64 + c] = (r == c) ? 1.0f : 0.0f;
    }
    __syncthreads();

    for (int k = 0; k < 64; ++k) {
        float dv = 1.0f / M[k * 129 + k];
        if (tid < 128) rowk[tid] = M[k * 129 + tid] * dv;
        if (tid >= 128 && tid < 192) ck[tid - 128] = M[(tid - 128) * 129 + k];
        __syncthreads();
        for (int idx = tid; idx < 64 * 128; idx += 256) {
            int r = idx >> 7, c = idx & 127;
            float cur = M[r * 129 + c];
            M[r * 129 + c] = (r == k) ? rowk[c] : cur - ck[r] * rowk[c];
        }
        __syncthreads();
    }
    // Yinv[m][j] = M[m*129 + 64 + j]

    // phase 2
    for (int idx = tid; idx < 6144; idx += 256) {        // Wx rows 0..95 of Wxt
        int k = idx >> 6, j = idx & 63;
        float s = 0.0f;
        if (k < 64) {
            #pragma unroll 8
            for (int m = 0; m < 64; ++m) s += A[m * 64 + k] * M[m * 129 + 64 + j];
        } else {
            int ku = k - 64;
            #pragma unroll 8
            for (int m = 0; m < 64; ++m) s += B1[m * 32 + ku] * M[m * 129 + 64 + j];
        }
        WxL[idx] = s;
        ws[WS_WXT + idx] = s;
    }
    for (int idx = tid; idx < 4096; idx += 256) {        // Wxw rows 96..159 of Wxt
        int k = idx >> 6, j = idx & 63;
        float s = 0.0f;
        #pragma unroll 8
        for (int m = 0; m < 64; ++m) s += B2[m * 64 + k] * M[m * 129 + 64 + j];
        WxwL[idx] = s;
        ws[WS_WXT + 6144 + idx] = s;
    }
    for (int idx = tid; idx < 2048; idx += 256)          // Wxt rows 160..191 = 0
        ws[WS_WXT + 10240 + idx] = 0.0f;
    for (int idx = tid; idx < 2048; idx += 256) {        // Wzu rows 160..191 of Wzt
        int k = idx >> 6, j = idx & 63;
        ws[WS_WZT + 10240 + idx] = D21[j * 32 + k] / lam[j];
    }
    for (int idx = tid; idx < 5120; idx += 256) {        // Wyt rows 0..159
        int k = idx >> 5, j = idx & 31;
        float v = (k < 64) ? C1[j * 64 + k]
                : (k < 96) ? D11[j * 32 + (k - 64)]
                           : D12[j * 64 + (k - 96)];
        ws[WS_WYT + idx] = v;
    }
    for (int idx = tid; idx < 1024; idx += 256)          // Wyt rows 160..191 = 0
        ws[WS_WYT + 5120 + idx] = 0.0f;
    __syncthreads();

    // phase 3: Wzz, Wwz
    for (int idx = tid; idx < 6144; idx += 256) {
        int k = idx >> 6, j = idx & 63;
        float s = 0.0f;
        #pragma unroll 8
        for (int m = 0; m < 64; ++m) s += WxL[k * 64 + m] * C2[j * 64 + m];
        ws[WS_WZT + idx] = s / lam[j];
    }
    for (int idx = tid; idx < 4096; idx += 256) {
        int k = idx >> 6, j = idx & 63;
        float s = 0.0f;
        #pragma unroll 8
        for (int m = 0; m < 64; ++m) s += WxwL[k * 64 + m] * C2[j * 64 + m];
        ws[WS_WZT + 6144 + idx] = s / lam[j];
    }
}

// ---------------------------------------------------------------------------
// Scan: 256 blocks (1 chain) x 512 threads (8 waves, 2/SIMD: one Z + one X).
// S (192) = [x(64); u(32); w(64); uq(32)], ping-pong; one barrier per step.
// Lane: p = lane&15 (K-slice of 12 floats = 3x ds_read_b128), o = lane>>4.
// Row id r_ = 4g+o in [0,16); outputs contiguous: Z -> w[4r_..4r_+3],
// X -> x[4r_..4r_+3] and y[2r_..2r_+1].  Reductions: DPP row_ror adds.
// u: 64-step LDS ring (loads drained once/64 steps); y: 16-step reg batch.
__global__ __launch_bounds__(512, 2) void rnn_kernel(const float* __restrict__ xp,
                                                     const float* __restrict__ ws,
                                                     float* __restrict__ out) {
    const int b    = blockIdx.x;
    const int tid  = threadIdx.x;
    const int wv   = tid >> 6;
    const int lane = tid & 63;
    const int p    = lane & 15;
    const int o    = lane >> 4;

    __shared__ __align__(16) float sbuf[2][192];
    __shared__ __align__(16) float uring[2][2048];   // 2 x 64 steps x 32

    const float* __restrict__ Wzt = ws + WS_WZT;
    const float* __restrict__ Wxt = ws + WS_WXT;
    const float* __restrict__ Wyt = ws + WS_WYT;

    const float4* __restrict__ xp4 = (const float4*)(xp + (size_t)b * (TT * NUS));
    float4* ur4 = (float4*)uring;                    // ring block k at float4 ofs 512k
    const size_t yb   = (size_t)b * (TT * NYS);
    const size_t xoff = (size_t)BBATCH * TT * NYS;

    // prologue: S_{-1} = [0;0;0;u_0] in sbuf[1]; ring block 0 = u_0..63
    if (tid < 40)              ((float4*)&sbuf[1][0])[tid] = make_float4(0.f, 0.f, 0.f, 0.f);
    else if (tid < 48)         ((float4*)&sbuf[1][160])[tid - 40] = xp4[tid - 40];
    ur4[tid] = xp4[tid];
    __syncthreads();

    if (wv < 4) {
        // ===================== Z waves: z -> tanh -> w =====================
        const int g   = wv;
        const int rz  = 4 * g + o;
        const int jzb = 4 * rz;
        v2f wz2[6][4];
        #pragma unroll
        for (int k2 = 0; k2 < 6; ++k2) {
            int row = 12 * p + 2 * k2;
            #pragma unroll
            for (int r = 0; r < 4; ++r)
                wz2[k2][r] = (v2f){ Wzt[row * 64 + jzb + r], Wzt[(row + 1) * 64 + jzb + r] };
        }

        float4 ureg[8];                              // live only in wave g==2

        #pragma unroll 4
        for (int i = 0; i < TT; ++i) {
            const int rp = (i + 1) & 1, wp = i & 1;

            if (g == 2) {                            // 64-step u prefetch
                if ((i & 63) == 0 && i + 64 < TT) {
                    #pragma unroll
                    for (int q = 0; q < 8; ++q)
                        ureg[q] = xp4[(i + 64) * 8 + q * 64 + lane];
                }
                if ((i & 63) == 32 && i + 96 <= TT) {
                    int nb = ((i >> 6) + 1) & 1;
                    #pragma unroll
                    for (int q = 0; q < 8; ++q)
                        ur4[nb * 512 + q * 64 + lane] = ureg[q];
                }
            }

            const float4* sb4 = (const float4*)&sbuf[rp][0];
            float4 A0 = sb4[3 * p], A1 = sb4[3 * p + 1], A2 = sb4[3 * p + 2];
            v2f av[6];
            av[0] = (v2f){A0.x, A0.y}; av[1] = (v2f){A0.z, A0.w};
            av[2] = (v2f){A1.x, A1.y}; av[3] = (v2f){A1.z, A1.w};
            av[4] = (v2f){A2.x, A2.y}; av[5] = (v2f){A2.z, A2.w};

            v2f c0 = {0.f, 0.f}, c1 = c0, c2 = c0, c3 = c0;
            #pragma unroll
            for (int k2 = 0; k2 < 6; ++k2) {
                c0 += av[k2] * wz2[k2][0]; c1 += av[k2] * wz2[k2][1];
                c2 += av[k2] * wz2[k2][2]; c3 += av[k2] * wz2[k2][3];
            }
            float s0 = row_sum16(c0.x + c0.y);
            float s1 = row_sum16(c1.x + c1.y);
            float s2 = row_sum16(c2.x + c2.y);
            float s3 = row_sum16(c3.x + c3.y);
            if (p == 0)
                ((float4*)&sbuf[wp][96])[rz] =
                    make_float4(fast_tanh(s0), fast_tanh(s1), fast_tanh(s2), fast_tanh(s3));

            // u plumbing: S_i.u <- S_{i-1}.uq ; S_i.uq <- ring[i+1]
            if (g == 0 && lane < 8)
                ((float4*)&sbuf[wp][64])[lane] = ((const float4*)&sbuf[rp][160])[lane];
            if (g == 1 && lane < 8) {
                int s = i + 1;
                int cb = (s >> 6) & 1;
                ((float4*)&sbuf[wp][160])[lane] = ur4[cb * 512 + (s & 63) * 8 + lane];
            }
            __syncthreads();
        }
    } else {
        // ===================== X waves: x' and y =====================
        const int g   = wv - 4;
        const int rx  = 4 * g + o;
        const int jxb = 4 * rx;
        const int jyb = 2 * rx;
        v2f wx2[6][4], wy2[6][2];
        #pragma unroll
        for (int k2 = 0; k2 < 6; ++k2) {
            int row = 12 * p + 2 * k2;
            #pragma unroll
            for (int r = 0; r < 4; ++r)
                wx2[k2][r] = (v2f){ Wxt[row * 64 + jxb + r], Wxt[(row + 1) * 64 + jxb + r] };
            wy2[k2][0] = (v2f){ Wyt[row * 32 + jyb],     Wyt[(row + 1) * 32 + jyb] };
            wy2[k2][1] = (v2f){ Wyt[row * 32 + jyb + 1], Wyt[(row + 1) * 32 + jyb + 1] };
        }

        float2 ybat[16];

        auto compute = [&](const float* S, float& sx0, float& sx1, float& sx2,
                           float& sx3, float& sy0, float& sy1) {
            const float4* sb4 = (const float4*)S;
            float4 A0 = sb4[3 * p], A1 = sb4[3 * p + 1], A2 = sb4[3 * p + 2];
            v2f av[6];
            av[0] = (v2f){A0.x, A0.y}; av[1] = (v2f){A0.z, A0.w};
            av[2] = (v2f){A1.x, A1.y}; av[3] = (v2f){A1.z, A1.w};
            av[4] = (v2f){A2.x, A2.y}; av[5] = (v2f){A2.z, A2.w};
            v2f c0 = {0.f, 0.f}, c1 = c0, c2 = c0, c3 = c0, d0 = c0, d1 = c0;
            #pragma unroll
            for (int k2 = 0; k2 < 6; ++k2) {
                c0 += av[k2] * wx2[k2][0]; c1 += av[k2] * wx2[k2][1];
                c2 += av[k2] * wx2[k2][2]; c3 += av[k2] * wx2[k2][3];
                d0 += av[k2] * wy2[k2][0]; d1 += av[k2] * wy2[k2][1];
            }
            sx0 = row_sum16(c0.x + c0.y);
            sx1 = row_sum16(c1.x + c1.y);
            sx2 = row_sum16(c2.x + c2.y);
            sx3 = row_sum16(c3.x + c3.y);
            sy0 = row_sum16(d0.x + d0.y);
            sy1 = row_sum16(d1.x + d1.y);
        };

        #pragma unroll 16
        for (int i = 0; i < TT; ++i) {
            const int rp = (i + 1) & 1, wp = i & 1;
            float sx0, sx1, sx2, sx3, sy0, sy1;
            compute(&sbuf[rp][0], sx0, sx1, sx2, sx3, sy0, sy1);

            if (p == 0)
                ((float4*)&sbuf[wp][0])[rx] = make_float4(sx0, sx1, sx2, sx3);
            ybat[(i + 15) & 15] = make_float2(sy0, sy1);   // y_{i-1}
            if ((i & 15) == 0 && i >= 16 && p == 0) {
                size_t base = yb + (size_t)(i - 16) * NYS + jyb;
                #pragma unroll
                for (int s = 0; s < 16; ++s)
                    *(float2*)&out[base + (size_t)s * NYS] = ybat[s];
            }
            __syncthreads();
        }

        // epilogue: y_2047 + x_final from S_2047 (sbuf[1])
        {
            float sx0, sx1, sx2, sx3, sy0, sy1;
            compute(&sbuf[1][0], sx0, sx1, sx2, sx3, sy0, sy1);
            ybat[15] = make_float2(sy0, sy1);
            if (p == 0) {
                *(float4*)&out[xoff + (size_t)b * 64 + jxb] =
                    make_float4(sx0, sx1, sx2, sx3);
                size_t base = yb + (size_t)(TT - 16) * NYS + jyb;
                #pragma unroll
                for (int s = 0; s < 16; ++s)
                    *(float2*)&out[base + (size_t)s * NYS] = ybat[s];
            }
        }
    }
}

// ---------------------------------------------------------------------------
extern "C" void kernel_launch(void* const* d_in, const int* in_sizes, int n_in,
                              void* d_out, int out_size, void* d_ws, size_t ws_size,
                              hipStream_t stream) {
    const float* xp  = (const float*)d_in[0];
    const float* Y   = (const float*)d_in[1];
    const float* lam = (const float*)d_in[2];
    const float* A   = (const float*)d_in[3];
    const float* B1  = (const float*)d_in[4];
    const float* B2  = (const float*)d_in[5];
    const float* C1  = (const float*)d_in[6];
    const float* D11 = (const float*)d_in[7];
    const float* D12 = (const float*)d_in[8];
    const float* C2  = (const float*)d_in[9];
    const float* D21 = (const float*)d_in[10];
    float* out = (float*)d_out;
    float* ws  = (float*)d_ws;

    hipLaunchKernelGGL(setup_kernel, dim3(1), dim3(256), 0, stream,
                       Y, lam, A, B1, B2, C1, D11, D12, C2, D21, ws);
    hipLaunchKernelGGL(rnn_kernel, dim3(256), dim3(512), 0, stream, xp, ws, out);
}